// Round 1
// baseline (320.654 us; speedup 1.0000x reference)
//
#include <hip/hip_runtime.h>
#include <math.h>

// Capsule dynamic routing, fused single kernel.
// x: [B=256, R=1152, I=8] f32
// W: [C=10, R=1152, I=8, O=16] f32
// out: [B=256, C=10, O=16] f32
//
// One block per (c,b). 384 threads; thread t owns rows r = t, t+384, t+768.
// priors rows live in registers (3 x 16 floats/thread). Routing iterations
// use wave shfl_xor butterflies + tiny LDS cross-wave reduction.

#define C_CAPS 10
#define B_SZ   256
#define R_SZ   1152
#define I_SZ   8
#define O_SZ   16
#define T_THREADS 384
#define RPT 3            // rows per thread = R / T
#define NW 6             // waves per block

__global__ __launch_bounds__(T_THREADS) void capsule_kernel(
    const float* __restrict__ x,
    const float* __restrict__ w,
    float* __restrict__ out)
{
    const int c = blockIdx.x >> 8;        // / B_SZ
    const int b = blockIdx.x & 255;       // % B_SZ
    const int t = (int)threadIdx.x;
    const int lane = t & 63;
    const int wid = t >> 6;

    __shared__ float red_max[NW];
    __shared__ float red_sum[NW];
    __shared__ float red_s[NW][O_SZ];

    // ---- priors: P[j][o] for rows r = t + j*T ----
    float P[RPT][O_SZ];
    #pragma unroll
    for (int j = 0; j < RPT; ++j) {
        const int r = t + j * T_THREADS;
        const float* xp = x + ((size_t)b * R_SZ + r) * I_SZ;
        const float4 xv0 = *(const float4*)(xp);
        const float4 xv1 = *(const float4*)(xp + 4);
        const float xi[I_SZ] = {xv0.x, xv0.y, xv0.z, xv0.w,
                                xv1.x, xv1.y, xv1.z, xv1.w};
        const float* wr = w + ((size_t)c * R_SZ + r) * (I_SZ * O_SZ);
        float acc[O_SZ];
        #pragma unroll
        for (int o = 0; o < O_SZ; ++o) acc[o] = 0.0f;
        #pragma unroll
        for (int i = 0; i < I_SZ; ++i) {
            #pragma unroll
            for (int o4 = 0; o4 < O_SZ / 4; ++o4) {
                const float4 wv = *(const float4*)(wr + i * O_SZ + o4 * 4);
                acc[o4 * 4 + 0] = fmaf(xi[i], wv.x, acc[o4 * 4 + 0]);
                acc[o4 * 4 + 1] = fmaf(xi[i], wv.y, acc[o4 * 4 + 1]);
                acc[o4 * 4 + 2] = fmaf(xi[i], wv.z, acc[o4 * 4 + 2]);
                acc[o4 * 4 + 3] = fmaf(xi[i], wv.w, acc[o4 * 4 + 3]);
            }
        }
        #pragma unroll
        for (int o = 0; o < O_SZ; ++o) P[j][o] = acc[o];
    }

    float logit[RPT];
    #pragma unroll
    for (int j = 0; j < RPT; ++j) logit[j] = 0.0f;

    float outv[O_SZ];

    for (int it = 0; it < 3; ++it) {
        // ---- probs over r (softmax of per-row scalar logits) ----
        float p[RPT];
        if (it == 0) {
            const float u = 1.0f / (float)R_SZ;
            #pragma unroll
            for (int j = 0; j < RPT; ++j) p[j] = u;
        } else {
            float lm = logit[0];
            #pragma unroll
            for (int j = 1; j < RPT; ++j) lm = fmaxf(lm, logit[j]);
            #pragma unroll
            for (int m = 32; m >= 1; m >>= 1) lm = fmaxf(lm, __shfl_xor(lm, m, 64));
            if (lane == 0) red_max[wid] = lm;
            __syncthreads();
            float gm = red_max[0];
            #pragma unroll
            for (int k = 1; k < NW; ++k) gm = fmaxf(gm, red_max[k]);

            float e[RPT];
            float zp = 0.0f;
            #pragma unroll
            for (int j = 0; j < RPT; ++j) { e[j] = expf(logit[j] - gm); zp += e[j]; }
            #pragma unroll
            for (int m = 32; m >= 1; m >>= 1) zp += __shfl_xor(zp, m, 64);
            if (lane == 0) red_sum[wid] = zp;
            __syncthreads();
            float Z = red_sum[0];
            #pragma unroll
            for (int k = 1; k < NW; ++k) Z += red_sum[k];
            const float invZ = 1.0f / Z;
            #pragma unroll
            for (int j = 0; j < RPT; ++j) p[j] = e[j] * invZ;
        }

        // ---- s[o] = sum_r p[r] * P[r][o] ----
        float sa[O_SZ];
        #pragma unroll
        for (int o = 0; o < O_SZ; ++o) sa[o] = 0.0f;
        #pragma unroll
        for (int j = 0; j < RPT; ++j) {
            #pragma unroll
            for (int o = 0; o < O_SZ; ++o)
                sa[o] = fmaf(p[j], P[j][o], sa[o]);
        }
        #pragma unroll
        for (int m = 1; m < 64; m <<= 1) {
            #pragma unroll
            for (int o = 0; o < O_SZ; ++o)
                sa[o] += __shfl_xor(sa[o], m, 64);
        }
        if (lane == 0) {
            #pragma unroll
            for (int o = 0; o < O_SZ; ++o) red_s[wid][o] = sa[o];
        }
        __syncthreads();

        float s[O_SZ];
        #pragma unroll
        for (int o = 0; o < O_SZ; ++o) {
            float v = red_s[0][o];
            #pragma unroll
            for (int k = 1; k < NW; ++k) v += red_s[k][o];
            s[o] = v;
        }

        // ---- squash ----
        float sq = 0.0f;
        #pragma unroll
        for (int o = 0; o < O_SZ; ++o) sq = fmaf(s[o], s[o], sq);
        const float scale = sq / ((1.0f + sq) * sqrtf(sq));
        #pragma unroll
        for (int o = 0; o < O_SZ; ++o) outv[o] = scale * s[o];

        // ---- logit update (iters 0,1) ----
        if (it < 2) {
            #pragma unroll
            for (int j = 0; j < RPT; ++j) {
                float d = 0.0f;
                #pragma unroll
                for (int o = 0; o < O_SZ; ++o)
                    d = fmaf(P[j][o], outv[o], d);
                logit[j] += d;
            }
        }
        __syncthreads();   // protect LDS buffers before next iteration re-writes
    }

    // ---- write out[b, c, :] ----
    if (t == 0) {
        float* op = out + ((size_t)b * C_CAPS + c) * O_SZ;
        #pragma unroll
        for (int o4 = 0; o4 < 4; ++o4)
            *(float4*)(op + o4 * 4) = make_float4(outv[o4 * 4 + 0], outv[o4 * 4 + 1],
                                                  outv[o4 * 4 + 2], outv[o4 * 4 + 3]);
    }
}

extern "C" void kernel_launch(void* const* d_in, const int* in_sizes, int n_in,
                              void* d_out, int out_size, void* d_ws, size_t ws_size,
                              hipStream_t stream) {
    const float* x = (const float*)d_in[0];
    const float* w = (const float*)d_in[1];
    float* out = (float*)d_out;
    dim3 grid(C_CAPS * B_SZ);
    dim3 block(T_THREADS);
    hipLaunchKernelGGL(capsule_kernel, grid, block, 0, stream, x, w, out);
}

// Round 2
// 98.099 us; speedup vs baseline: 3.2687x; 3.2687x over previous
//
#include <hip/hip_runtime.h>
#include <math.h>

// Capsule dynamic routing, fused single kernel — coalesced-W version.
// x: [B=256, R=1152, I=8] f32
// W: [C=10, R=1152, I=8, O=16] f32
// out: [B=256, C=10, O=16] f32
//
// One block per (c,b). 384 threads = 96 groups of 4 lanes.
// Group g owns rows r = g + j*96 (j=0..11); lane q = t&3 owns o-quad q*4..q*4+3.
// W loads: 4 lanes of a group read 64B contiguous -> fully coalesced lines.
// Priors P[12][4] live in registers. Routing uses shfl_xor reductions:
//   over o  : masks {1,2}   (within 4-lane group)
//   over r  : masks {4..32} (across the wave's 16 groups) + LDS across 6 waves

#define C_CAPS 10
#define B_SZ   256
#define R_SZ   1152
#define I_SZ   8
#define O_SZ   16
#define T_THREADS 384
#define NGROUP 96        // T/4 groups
#define RPT 12           // rows per group = R / NGROUP
#define NW 6             // waves per block

__global__ __launch_bounds__(T_THREADS) void capsule_kernel(
    const float* __restrict__ x,
    const float* __restrict__ w,
    float* __restrict__ out)
{
    const int c = blockIdx.x >> 8;        // / B_SZ
    const int b = blockIdx.x & 255;       // % B_SZ
    const int t = (int)threadIdx.x;
    const int lane = t & 63;
    const int wid = t >> 6;
    const int q = t & 3;                  // o-quad index (o = q*4..q*4+3)
    const int g = t >> 2;                 // group id 0..95

    __shared__ float red_max[NW];
    __shared__ float red_sum[NW];
    __shared__ float red_s[NW][4][4];

    // ---- priors: P[j][k] = priors[r = g + j*96][o = q*4+k] ----
    float P[RPT][4];
    #pragma unroll
    for (int j = 0; j < RPT; ++j) {
        const int r = g + j * NGROUP;
        const float* xp = x + ((size_t)b * R_SZ + r) * I_SZ;
        const float4 xv0 = *(const float4*)(xp);       // same addr across group: broadcast
        const float4 xv1 = *(const float4*)(xp + 4);
        const float xi[I_SZ] = {xv0.x, xv0.y, xv0.z, xv0.w,
                                xv1.x, xv1.y, xv1.z, xv1.w};
        const float* wr = w + ((size_t)c * R_SZ + r) * (I_SZ * O_SZ) + q * 4;
        float a0 = 0.f, a1 = 0.f, a2 = 0.f, a3 = 0.f;
        #pragma unroll
        for (int i = 0; i < I_SZ; ++i) {
            const float4 wv = *(const float4*)(wr + i * O_SZ);
            a0 = fmaf(xi[i], wv.x, a0);
            a1 = fmaf(xi[i], wv.y, a1);
            a2 = fmaf(xi[i], wv.z, a2);
            a3 = fmaf(xi[i], wv.w, a3);
        }
        P[j][0] = a0; P[j][1] = a1; P[j][2] = a2; P[j][3] = a3;
    }

    float logit[RPT];
    #pragma unroll
    for (int j = 0; j < RPT; ++j) logit[j] = 0.0f;

    float outq[4];   // this lane's o-quad of the squashed output

    for (int it = 0; it < 3; ++it) {
        // ---- probs over r (softmax of per-row scalar logits) ----
        float p[RPT];
        if (it == 0) {
            const float u = 1.0f / (float)R_SZ;
            #pragma unroll
            for (int j = 0; j < RPT; ++j) p[j] = u;
        } else {
            float lm = logit[0];
            #pragma unroll
            for (int j = 1; j < RPT; ++j) lm = fmaxf(lm, logit[j]);
            // logits replicated within group -> reduce across 16 groups of wave
            #pragma unroll
            for (int m = 4; m <= 32; m <<= 1) lm = fmaxf(lm, __shfl_xor(lm, m, 64));
            if (lane == 0) red_max[wid] = lm;
            __syncthreads();
            float gm = red_max[0];
            #pragma unroll
            for (int k = 1; k < NW; ++k) gm = fmaxf(gm, red_max[k]);

            float zp = 0.0f;
            #pragma unroll
            for (int j = 0; j < RPT; ++j) { p[j] = expf(logit[j] - gm); zp += p[j]; }
            #pragma unroll
            for (int m = 4; m <= 32; m <<= 1) zp += __shfl_xor(zp, m, 64);
            if (lane == 0) red_sum[wid] = zp;
            __syncthreads();
            float Z = red_sum[0];
            #pragma unroll
            for (int k = 1; k < NW; ++k) Z += red_sum[k];
            const float invZ = 1.0f / Z;
            #pragma unroll
            for (int j = 0; j < RPT; ++j) p[j] *= invZ;
        }

        // ---- s[o-quad] = sum_r p[r] * P[r][o-quad] ----
        float sa[4] = {0.f, 0.f, 0.f, 0.f};
        #pragma unroll
        for (int j = 0; j < RPT; ++j) {
            sa[0] = fmaf(p[j], P[j][0], sa[0]);
            sa[1] = fmaf(p[j], P[j][1], sa[1]);
            sa[2] = fmaf(p[j], P[j][2], sa[2]);
            sa[3] = fmaf(p[j], P[j][3], sa[3]);
        }
        // reduce across the wave's 16 groups (same q lanes)
        #pragma unroll
        for (int m = 4; m <= 32; m <<= 1) {
            sa[0] += __shfl_xor(sa[0], m, 64);
            sa[1] += __shfl_xor(sa[1], m, 64);
            sa[2] += __shfl_xor(sa[2], m, 64);
            sa[3] += __shfl_xor(sa[3], m, 64);
        }
        if (lane < 4) {   // one writer per (wave, q)
            red_s[wid][lane][0] = sa[0];
            red_s[wid][lane][1] = sa[1];
            red_s[wid][lane][2] = sa[2];
            red_s[wid][lane][3] = sa[3];
        }
        __syncthreads();

        float sq_[4];
        #pragma unroll
        for (int k = 0; k < 4; ++k) {
            float v = red_s[0][q][k];
            #pragma unroll
            for (int ww = 1; ww < NW; ++ww) v += red_s[ww][q][k];
            sq_[k] = v;
        }

        // ---- squash: need full ||s||^2 (sum across the 4 quads in group) ----
        float nrm = sq_[0]*sq_[0] + sq_[1]*sq_[1] + sq_[2]*sq_[2] + sq_[3]*sq_[3];
        nrm += __shfl_xor(nrm, 1, 64);
        nrm += __shfl_xor(nrm, 2, 64);
        const float scale = nrm / ((1.0f + nrm) * sqrtf(nrm));
        #pragma unroll
        for (int k = 0; k < 4; ++k) outq[k] = scale * sq_[k];

        // ---- logit update (iters 0,1): logit[r] += sum_o P[r][o]*out[o] ----
        if (it < 2) {
            #pragma unroll
            for (int j = 0; j < RPT; ++j) {
                float d = P[j][0]*outq[0] + P[j][1]*outq[1]
                        + P[j][2]*outq[2] + P[j][3]*outq[3];
                d += __shfl_xor(d, 1, 64);
                d += __shfl_xor(d, 2, 64);
                logit[j] += d;
            }
        }
        __syncthreads();   // protect LDS buffers before next iteration re-writes
    }

    // ---- write out[b, c, :]: threads 0..3 hold quads 0..3 ----
    if (t < 4) {
        float* op = out + ((size_t)b * C_CAPS + c) * O_SZ + q * 4;
        *(float4*)op = make_float4(outq[0], outq[1], outq[2], outq[3]);
    }
}

extern "C" void kernel_launch(void* const* d_in, const int* in_sizes, int n_in,
                              void* d_out, int out_size, void* d_ws, size_t ws_size,
                              hipStream_t stream) {
    const float* x = (const float*)d_in[0];
    const float* w = (const float*)d_in[1];
    float* out = (float*)d_out;
    dim3 grid(C_CAPS * B_SZ);
    dim3 block(T_THREADS);
    hipLaunchKernelGGL(capsule_kernel, grid, block, 0, stream, x, w, out);
}